// Round 10
// baseline (388.706 us; speedup 1.0000x reference)
//
#include <hip/hip_runtime.h>
#include <hip/hip_bf16.h>

// B=256, IN=512, OUT=512
//   y_mean = x_mean @ A_mean + b_mean
//   y_var  = diag_embed( (diag(x_var)+x_mean^2) @ A_var + diag(A^T Cov A) + b_var )
// term2[b,o] = sum_i A[i,o] * (x_var[b] @ A)[i,o]  -> stacked GEMM + weighted colsum
//
// k_gemm2 (new structure): BM=128 x BN=64, wave-tile 32x64. Whole-K A^T panel
// (64KB bf16, superrow-swizzled image) staged into LDS ONCE (single barrier);
// K-loop has NO barriers: X f32 flows global->VGPR->cvt->MFMA, compiler
// software-pipelines the loads. XCD-aware mapping keeps an mtile's 8 ntile
// partners on one XCD (X read from HBM once, L2 serves the reuse).

typedef __bf16 bf16x8 __attribute__((ext_vector_type(8)));
typedef float f32x4 __attribute__((ext_vector_type(4)));

__device__ inline ushort f2bf(float f) {
    union { float f; unsigned u; } x; x.f = f;
    unsigned u = x.u + 0x7fffu + ((x.u >> 16) & 1u);   // RNE
    return (ushort)(u >> 16);
}

__device__ inline void gload16(const void* g, void* l) {
    __builtin_amdgcn_global_load_lds(
        (const __attribute__((address_space(1))) void*)g,
        (__attribute__((address_space(3))) void*)l, 16, 0, 0);
}

// ---- kernel 1: A_mean -> bf16 A^T images, BN=64 whole-K panels ----
// Per nt (8 panels, 64KB each): [ks=16][superrow s=32][chunk c=8][8 bf16]
//   lc = c ^ (s&7); h = lc>>2; g = lc&3; row r = 2s+h (0..63); o = nt*64+r;
//   value[e] = A[ks*32 + g*8 + e][o]
__global__ void k_prep_at(const float* __restrict__ am, ushort* __restrict__ abt) {
    int C = blockIdx.x * 256 + threadIdx.x;   // chunk id 0..32767
    int nt = C >> 12;
    int L  = C & 4095;
    int ks = L >> 8;
    int rem = L & 255;
    int s = rem >> 3, c = rem & 7;
    int lc = c ^ (s & 7);
    int h = lc >> 2, g = lc & 3;
    int r = 2 * s + h;
    int o = nt * 64 + r;
    int j0 = ks * 32 + g * 8;
    ushort u[8];
    #pragma unroll
    for (int e = 0; e < 8; ++e) u[e] = f2bf(am[(j0 + e) * 512 + o]);
    *(int4*)(abt + (long)C * 8) = *(int4*)u;
}

// ---- kernel 2: xx[b][i] = x_var[b,i,i] + x_mean^2 ----
__global__ void k_diag(const float* __restrict__ xv, const float* __restrict__ xm,
                       float* __restrict__ xx) {
    int idx = blockIdx.x * 256 + threadIdx.x;     // b*512+i
    int b = idx >> 9, i = idx & 511;
    float m = xm[idx];
    xx[idx] = xv[(long)b * 262144 + i * 513] + m * m;
}

// ---- kernel 3: partial small GEMMs: yp/tp[ic][b][o] over 64-i chunks ----
__global__ void k_t1(const float* __restrict__ xm, const float* __restrict__ xx,
                     const float* __restrict__ am, const float* __restrict__ av,
                     float* __restrict__ yp, float* __restrict__ tp) {
    __shared__ float S[2][64];
    int t = threadIdx.x;
    int b  = blockIdx.x >> 3;
    int ic = blockIdx.x & 7;
    int i0 = ic * 64;
    if (t < 128) {
        int which = t >> 6, ii = t & 63;
        const float* src = which ? xx : xm;
        S[which][ii] = src[b * 512 + i0 + ii];
    }
    __syncthreads();
    int mat = t >> 7;                 // wave-uniform: 0 -> am/ym, 1 -> av/t1
    int o4 = t & 127;
    const float* M = mat ? av : am;
    const float* Sv = S[mat];
    f32x4 acc = {0.f, 0.f, 0.f, 0.f};
    #pragma unroll 8
    for (int ii = 0; ii < 64; ++ii) {
        f32x4 a = *(const f32x4*)(M + (long)(i0 + ii) * 512 + o4 * 4);
        float s = Sv[ii];
        acc[0] = fmaf(s, a[0], acc[0]);
        acc[1] = fmaf(s, a[1], acc[1]);
        acc[2] = fmaf(s, a[2], acc[2]);
        acc[3] = fmaf(s, a[3], acc[3]);
    }
    float* dst = (mat ? tp : yp) + ((long)ic * 256 + b) * 512 + o4 * 4;
    *(f32x4*)dst = acc;
}

// ---- kernel 4: MFMA GEMM, A once in LDS, barrier-free K-loop, X in regs ----
__global__ __launch_bounds__(256, 2) void k_gemm2(
        const float*  __restrict__ xv,    // Xflat [131072][512] f32
        const ushort* __restrict__ abt,   // A^T panels [8][16][32][8][8bf16]
        const float*  __restrict__ amean, // A f32 [j][o]
        float* __restrict__ p2,           // [256][4][512]
        float* __restrict__ yvar)         // [256][512][512]
{
    __shared__ ushort ldsA[32768];        // 64KB whole-K A^T panel
    __shared__ float  red[4][64];

    int t = threadIdx.x;
    int lane = t & 63;
    int w = t >> 6;

    int bid = blockIdx.x;
    int xcd = bid & 7;
    int rr  = bid >> 3;                   // 0..1023
    int nt  = rr & 7;
    int mtile = xcd + (rr >> 3) * 8;      // 0..1023, fixed XCD per mtile
    long m0 = (long)mtile * 128;
    int n0 = nt * 64;
    int msub = mtile & 3;
    int b = mtile >> 2;

    // stage whole-K A panel (64KB) once
    {
        const char* src = (const char*)abt + (long)nt * 65536 + w * 16384 + lane * 16;
        char* dst = (char*)ldsA + w * 16384;
        #pragma unroll
        for (int q = 0; q < 16; ++q)
            gload16(src + q * 1024, dst + q * 1024);
    }
    __syncthreads();                      // the only barrier before epilogue

    f32x4 acc[2][4];
    #pragma unroll
    for (int mf = 0; mf < 2; ++mf)
        #pragma unroll
        for (int nf = 0; nf < 4; ++nf)
            acc[mf][nf] = (f32x4){0.f, 0.f, 0.f, 0.f};

    int rl = lane & 15;
    int g  = lane >> 4;                   // k-octet
    const float* xr0 = xv + (m0 + w * 32 + rl) * 512 + g * 8;
    float* zb = yvar + ((long)b * 512 + msub * 128 + nt * 16) * 512;
    float4 z = make_float4(0.f, 0.f, 0.f, 0.f);

    #pragma unroll
    for (int ks = 0; ks < 16; ++ks) {
        float4 xa0 = *(const float4*)(xr0 + ks * 32);
        float4 xa1 = *(const float4*)(xr0 + ks * 32 + 4);
        float4 xb0 = *(const float4*)(xr0 + 16 * 512 + ks * 32);
        float4 xb1 = *(const float4*)(xr0 + 16 * 512 + ks * 32 + 4);
        if (ks < 8)                        // in-loop zero-fill (32KB/block total)
            *(float4*)(zb + ((long)ks * 256 + t) * 4) = z;
        bf16x8 af0, af1;
        af0[0] = (__bf16)xa0.x; af0[1] = (__bf16)xa0.y;
        af0[2] = (__bf16)xa0.z; af0[3] = (__bf16)xa0.w;
        af0[4] = (__bf16)xa1.x; af0[5] = (__bf16)xa1.y;
        af0[6] = (__bf16)xa1.z; af0[7] = (__bf16)xa1.w;
        af1[0] = (__bf16)xb0.x; af1[1] = (__bf16)xb0.y;
        af1[2] = (__bf16)xb0.z; af1[3] = (__bf16)xb0.w;
        af1[4] = (__bf16)xb1.x; af1[5] = (__bf16)xb1.y;
        af1[6] = (__bf16)xb1.z; af1[7] = (__bf16)xb1.w;
        #pragma unroll
        for (int nf = 0; nf < 4; ++nf) {
            int ro = nf * 16 + rl;
            int s = ro >> 1, h = ro & 1;
            bf16x8 bf = *(const bf16x8*)((const char*)ldsA + ks * 4096 + s * 128
                          + (((((h << 2) | g)) ^ (s & 7)) << 4));
            acc[0][nf] = __builtin_amdgcn_mfma_f32_16x16x32_bf16(
                af0, bf, acc[0][nf], 0, 0, 0);
            acc[1][nf] = __builtin_amdgcn_mfma_f32_16x16x32_bf16(
                af1, bf, acc[1][nf], 0, 0, 0);
        }
    }

    // epilogue: term2_partial[o] = sum_rows A[i,o]*C[i,o]
    #pragma unroll
    for (int nf = 0; nf < 4; ++nf) {
        float p = 0.f;
        int o = n0 + nf * 16 + rl;
        #pragma unroll
        for (int mf = 0; mf < 2; ++mf) {
            #pragma unroll
            for (int j = 0; j < 4; ++j) {
                int i = msub * 128 + w * 32 + mf * 16 + g * 4 + j;
                p += acc[mf][nf][j] * amean[i * 512 + o];
            }
        }
        p += __shfl_xor(p, 16, 64);
        p += __shfl_xor(p, 32, 64);
        if (lane < 16) red[w][nf * 16 + lane] = p;
    }
    __syncthreads();
    if (t < 64) {
        float v = red[0][t] + red[1][t] + red[2][t] + red[3][t];
        p2[((long)b * 4 + msub) * 512 + n0 + t] = v;
    }
}

// ---- kernel 5: ymean = bm + sum(yp); yvar diag = bv + sum(tp) + sum(p2) ----
__global__ void k_final(const float* __restrict__ yp, const float* __restrict__ tp,
                        const float* __restrict__ p2,
                        const float* __restrict__ bm, const float* __restrict__ bv,
                        float* __restrict__ ymean, float* __restrict__ yvar) {
    int idx = blockIdx.x * 256 + threadIdx.x;    // b*512+o
    int b = idx >> 9, o = idx & 511;
    float ym = bm[o], t1 = bv[o];
    #pragma unroll
    for (int ic = 0; ic < 8; ++ic) {
        ym += yp[((long)ic * 256 + b) * 512 + o];
        t1 += tp[((long)ic * 256 + b) * 512 + o];
    }
    long pb = (long)b * 2048 + o;
    t1 += p2[pb] + p2[pb + 512] + p2[pb + 1024] + p2[pb + 1536];
    ymean[idx] = ym;
    yvar[(long)idx * 512 + o] = t1;
}

extern "C" void kernel_launch(void* const* d_in, const int* in_sizes, int n_in,
                              void* d_out, int out_size, void* d_ws, size_t ws_size,
                              hipStream_t stream) {
    const float* x_mean = (const float*)d_in[0];
    const float* x_var  = (const float*)d_in[1];
    const float* A_mean = (const float*)d_in[2];
    const float* A_var  = (const float*)d_in[3];
    const float* b_mean = (const float*)d_in[4];
    const float* b_var  = (const float*)d_in[5];

    float* ymean = (float*)d_out;                  // [256,512]
    float* yvar  = (float*)d_out + 131072;         // [256,512,512]

    char* ws = (char*)d_ws;
    ushort* abt = (ushort*)ws;                          // 512 KB (A^T panels)
    float*  p2  = (float*)(ws + 512 * 1024);            // [256,4,512]   2 MB
    float*  yp  = (float*)(ws + 2560 * 1024);           // [8,256,512]   4 MB
    float*  tp  = (float*)(ws + 6656 * 1024);           // [8,256,512]   4 MB
    float*  xx  = (float*)(ws + 10752 * 1024);          // [256,512]     512 KB

    k_prep_at<<<128, 256, 0, stream>>>(A_mean, abt);
    k_diag<<<512, 256, 0, stream>>>(x_var, x_mean, xx);
    k_t1<<<2048, 256, 0, stream>>>(x_mean, xx, A_mean, A_var, yp, tp);
    k_gemm2<<<8192, 256, 0, stream>>>(x_var, abt, A_mean, p2, yvar);
    k_final<<<512, 256, 0, stream>>>(yp, tp, p2, b_mean, b_var, ymean, yvar);
}

// Round 12
// 273.027 us; speedup vs baseline: 1.4237x; 1.4237x over previous
//
#include <hip/hip_runtime.h>
#include <hip/hip_bf16.h>

// B=256, IN=512, OUT=512
//   y_mean = x_mean @ A_mean + b_mean
//   y_var  = diag_embed( (diag(x_var)+x_mean^2) @ A_var + diag(A^T Cov A) + b_var )
// term2[b,o] = sum_i A[i,o] * (x_var[b] @ A)[i,o]  -> stacked GEMM + weighted colsum
//
// k_gemm2: 8-wave 128x128 tile, BK=64, LDS dbuf (X as bf16 via reg-stage+cvt,
// A via global_load_lds). Pipeline: X(ks+2) global->reg issued at iter ks,
// written to LDS at iter ks+1 (2 compute-phases in flight -> HBM hidden);
// A glds issued FIRST each iter (oldest) so `s_waitcnt vmcnt(4)` before the
// raw s_barrier drains exactly A (L2-fast) and never the X prefetch.
// Zero-fill is a standalone kernel (r11 crash: it overfilled 2x; fixed k<32).

typedef __bf16 bf16x8 __attribute__((ext_vector_type(8)));
typedef __bf16 bf16x4 __attribute__((ext_vector_type(4)));
typedef float f32x4 __attribute__((ext_vector_type(4)));

__device__ inline ushort f2bf(float f) {
    union { float f; unsigned u; } x; x.f = f;
    unsigned u = x.u + 0x7fffu + ((x.u >> 16) & 1u);   // RNE
    return (ushort)(u >> 16);
}

__device__ inline void gload16(const void* g, void* l) {
    __builtin_amdgcn_global_load_lds(
        (const __attribute__((address_space(1))) void*)g,
        (__attribute__((address_space(3))) void*)l, 16, 0, 0);
}

// ---- kernel 1: A_mean -> bf16 A^T tile images (BK=64): abt[(nt*8+ks)*16KB] ----
// image byte = r*128 + ((c ^ (r&7))*16) + e*2 ; value = A[ks*64+c*8+e][nt*128+r]
__global__ void k_prep_at(const float* __restrict__ am, ushort* __restrict__ abt) {
    int C = blockIdx.x * 256 + threadIdx.x;   // chunk id 0..32767
    int nt = C >> 13;
    int L  = C & 8191;
    int ks = L >> 10;
    int rem = L & 1023;
    int r = rem >> 3, cs = rem & 7;
    int c = cs ^ (r & 7);
    int o = nt * 128 + r;
    int j0 = ks * 64 + c * 8;
    ushort u[8];
    #pragma unroll
    for (int e = 0; e < 8; ++e) u[e] = f2bf(am[(j0 + e) * 512 + o]);
    *(int4*)(abt + (long)C * 8) = *(int4*)u;
}

// ---- kernel 2: xx[b][i] = x_var[b,i,i] + x_mean^2 ----
__global__ void k_diag(const float* __restrict__ xv, const float* __restrict__ xm,
                       float* __restrict__ xx) {
    int idx = blockIdx.x * 256 + threadIdx.x;     // b*512+i
    int b = idx >> 9, i = idx & 511;
    float m = xm[idx];
    xx[idx] = xv[(long)b * 262144 + i * 513] + m * m;
}

// ---- kernel 3: partial small GEMMs: yp/tp[ic][b][o] over 64-i chunks ----
__global__ void k_t1(const float* __restrict__ xm, const float* __restrict__ xx,
                     const float* __restrict__ am, const float* __restrict__ av,
                     float* __restrict__ yp, float* __restrict__ tp) {
    __shared__ float S[2][64];
    int t = threadIdx.x;
    int b  = blockIdx.x >> 3;
    int ic = blockIdx.x & 7;
    int i0 = ic * 64;
    if (t < 128) {
        int which = t >> 6, ii = t & 63;
        const float* src = which ? xx : xm;
        S[which][ii] = src[b * 512 + i0 + ii];
    }
    __syncthreads();
    int mat = t >> 7;                 // wave-uniform: 0 -> am/ym, 1 -> av/t1
    int o4 = t & 127;
    const float* M = mat ? av : am;
    const float* Sv = S[mat];
    f32x4 acc = {0.f, 0.f, 0.f, 0.f};
    #pragma unroll 8
    for (int ii = 0; ii < 64; ++ii) {
        f32x4 a = *(const f32x4*)(M + (long)(i0 + ii) * 512 + o4 * 4);
        float s = Sv[ii];
        acc[0] = fmaf(s, a[0], acc[0]);
        acc[1] = fmaf(s, a[1], acc[1]);
        acc[2] = fmaf(s, a[2], acc[2]);
        acc[3] = fmaf(s, a[3], acc[3]);
    }
    float* dst = (mat ? tp : yp) + ((long)ic * 256 + b) * 512 + o4 * 4;
    *(f32x4*)dst = acc;
}

// ---- kernel 4: zero-fill y_var (268MB; 16,777,216 float4s; diag written later) ----
__global__ void k_fillz(float* __restrict__ yvar) {
    int idx = blockIdx.x * 256 + threadIdx.x;      // 0..524287
    float4 z = make_float4(0.f, 0.f, 0.f, 0.f);
    #pragma unroll 8
    for (int k = 0; k < 32; ++k)                   // 524288*32 = 16,777,216 float4
        *(float4*)(yvar + ((long)k * 524288 + idx) * 4) = z;
}

// ---- kernel 5: MFMA GEMM, dbuf pipeline, X reg-staged 2-deep ----
__global__ __launch_bounds__(512, 4) void k_gemm2(
        const float*  __restrict__ xv,    // Xflat [131072][512] f32
        const ushort* __restrict__ abt,   // A^T BK=64 images [4][8][16KB]
        const float*  __restrict__ amean, // A f32 [j][o]
        float* __restrict__ p2)           // [256][4][512]
{
    __shared__ ushort ldsX[2][8192];      // 2 x 16KB bf16, 128 rows x 128B
    __shared__ ushort ldsA[2][8192];      // 2 x 16KB bf16
    __shared__ float  red[4][128];

    int t = threadIdx.x;
    int lane = t & 63;
    int w = t >> 6;                       // 0..7
    int wm = w >> 1, wn = w & 1;
    int rl = lane & 15, g = lane >> 4;

    int bid = blockIdx.x;
    int swz = (bid & 7) * 512 + (bid >> 3);   // bijective XCD swizzle (4096%8==0)
    int mtile = swz >> 2;                     // 0..1023
    int ntile = swz & 3;
    int n0 = ntile * 128;
    long m0 = (long)mtile * 128;
    int msub = mtile & 3;
    int b = mtile >> 2;

    f32x4 acc[2][4];
    #pragma unroll
    for (int mf = 0; mf < 2; ++mf)
        #pragma unroll
        for (int nf = 0; nf < 4; ++nf)
            acc[mf][nf] = (f32x4){0.f, 0.f, 0.f, 0.f};

    // X: instr j covers rows w*16 + j*4 + g, 16B chunk rl (256B/row contiguous)
    const float* xbase = xv + (m0 + w * 16 + g) * 512 + rl * 4;
    const char*  abase = (const char*)abt + (long)ntile * 131072 + w * 2048 + lane * 16;

    float4 xA[4], xB[4];

    auto loadXA = [&](int ks) {
        #pragma unroll
        for (int j = 0; j < 4; ++j)
            xA[j] = *(const float4*)(xbase + (long)j * 2048 + ks * 64);
    };
    auto loadXB = [&](int ks) {
        #pragma unroll
        for (int j = 0; j < 4; ++j)
            xB[j] = *(const float4*)(xbase + (long)j * 2048 + ks * 64);
    };
    auto gldsA = [&](int buf, int ks) {
        const char* src = abase + (long)ks * 16384;
        char* dst = (char*)ldsA[buf] + w * 2048;
        gload16(src, dst);
        gload16(src + 1024, dst + 1024);
    };
    auto writeXA = [&](int buf) {
        #pragma unroll
        for (int j = 0; j < 4; ++j) {
            int r = w * 16 + j * 4 + g;
            bf16x4 v;
            v[0] = (__bf16)xA[j].x; v[1] = (__bf16)xA[j].y;
            v[2] = (__bf16)xA[j].z; v[3] = (__bf16)xA[j].w;
            int off = r * 128 + (((rl >> 1) << 4) ^ ((r & 7) << 4)) + (rl & 1) * 8;
            *(bf16x4*)((char*)ldsX[buf] + off) = v;
        }
    };
    auto writeXB = [&](int buf) {
        #pragma unroll
        for (int j = 0; j < 4; ++j) {
            int r = w * 16 + j * 4 + g;
            bf16x4 v;
            v[0] = (__bf16)xB[j].x; v[1] = (__bf16)xB[j].y;
            v[2] = (__bf16)xB[j].z; v[3] = (__bf16)xB[j].w;
            int off = r * 128 + (((rl >> 1) << 4) ^ ((r & 7) << 4)) + (rl & 1) * 8;
            *(bf16x4*)((char*)ldsX[buf] + off) = v;
        }
    };
    auto compute = [&](int buf) {
        #pragma unroll
        for (int kc = 0; kc < 2; ++kc) {
            bf16x8 af[2], bfr[4];
            int kb = kc * 64 + g * 16;
            #pragma unroll
            for (int mf = 0; mf < 2; ++mf) {
                int r = wm * 32 + mf * 16 + rl;
                af[mf] = *(const bf16x8*)((const char*)ldsX[buf] + r * 128
                                          + (kb ^ ((r & 7) << 4)));
            }
            #pragma unroll
            for (int nf = 0; nf < 4; ++nf) {
                int r = wn * 64 + nf * 16 + rl;
                bfr[nf] = *(const bf16x8*)((const char*)ldsA[buf] + r * 128
                                           + (kb ^ ((r & 7) << 4)));
            }
            #pragma unroll
            for (int mf = 0; mf < 2; ++mf)
                #pragma unroll
                for (int nf = 0; nf < 4; ++nf)
                    acc[mf][nf] = __builtin_amdgcn_mfma_f32_16x16x32_bf16(
                        af[mf], bfr[nf], acc[mf][nf], 0, 0, 0);
        }
    };

    // prologue: A0 glds (oldest), X0 regs, X0->LDS, X1 regs in flight
    gldsA(0, 0);
    loadXA(0);
    writeXA(0);                            // compiler waits xA precisely
    loadXB(1);
    asm volatile("s_waitcnt vmcnt(4) lgkmcnt(0)" ::: "memory");  // A0 done; xB stays
    __builtin_amdgcn_s_barrier();
    __builtin_amdgcn_sched_barrier(0);

    #pragma unroll
    for (int ks = 0; ks < 8; ++ks) {
        const int p = ks & 1;
        if (ks <= 6) gldsA(1 - p, ks + 1);             // issued FIRST -> oldest
        if (ks <= 5) { if (p == 0) loadXA(ks + 2); else loadXB(ks + 2); }
        compute(p);
        if (ks <= 6) { if (p == 0) writeXB(1 - p); else writeXA(1 - p); }
        if (ks <= 5) {
            asm volatile("s_waitcnt vmcnt(4) lgkmcnt(0)" ::: "memory"); // drain A only
            __builtin_amdgcn_s_barrier();
            __builtin_amdgcn_sched_barrier(0);
        } else if (ks == 6) {
            asm volatile("s_waitcnt vmcnt(0) lgkmcnt(0)" ::: "memory");
            __builtin_amdgcn_s_barrier();
            __builtin_amdgcn_sched_barrier(0);
        }
    }

    // epilogue: term2_partial[o] = sum_rows A[i,o]*C[i,o]
    #pragma unroll
    for (int nf = 0; nf < 4; ++nf) {
        float p = 0.f;
        int o = n0 + wn * 64 + nf * 16 + rl;
        #pragma unroll
        for (int mf = 0; mf < 2; ++mf) {
            #pragma unroll
            for (int j = 0; j < 4; ++j) {
                int i = msub * 128 + wm * 32 + mf * 16 + g * 4 + j;
                p += acc[mf][nf][j] * amean[i * 512 + o];
            }
        }
        p += __shfl_xor(p, 16, 64);
        p += __shfl_xor(p, 32, 64);
        if (lane < 16) red[wm][wn * 64 + nf * 16 + lane] = p;
    }
    __syncthreads();
    if (t < 128) {
        float v = red[0][t] + red[1][t] + red[2][t] + red[3][t];
        p2[((long)b * 4 + msub) * 512 + n0 + t] = v;
    }
}

// ---- kernel 6: ymean = bm + sum(yp); yvar diag = bv + sum(tp) + sum(p2) ----
__global__ void k_final(const float* __restrict__ yp, const float* __restrict__ tp,
                        const float* __restrict__ p2,
                        const float* __restrict__ bm, const float* __restrict__ bv,
                        float* __restrict__ ymean, float* __restrict__ yvar) {
    int idx = blockIdx.x * 256 + threadIdx.x;    // b*512+o
    int b = idx >> 9, o = idx & 511;
    float ym = bm[o], t1 = bv[o];
    #pragma unroll
    for (int ic = 0; ic < 8; ++ic) {
        ym += yp[((long)ic * 256 + b) * 512 + o];
        t1 += tp[((long)ic * 256 + b) * 512 + o];
    }
    long pb = (long)b * 2048 + o;
    t1 += p2[pb] + p2[pb + 512] + p2[pb + 1024] + p2[pb + 1536];
    ymean[idx] = ym;
    yvar[(long)idx * 512 + o] = t1;
}

extern "C" void kernel_launch(void* const* d_in, const int* in_sizes, int n_in,
                              void* d_out, int out_size, void* d_ws, size_t ws_size,
                              hipStream_t stream) {
    const float* x_mean = (const float*)d_in[0];
    const float* x_var  = (const float*)d_in[1];
    const float* A_mean = (const float*)d_in[2];
    const float* A_var  = (const float*)d_in[3];
    const float* b_mean = (const float*)d_in[4];
    const float* b_var  = (const float*)d_in[5];

    float* ymean = (float*)d_out;                  // [256,512]
    float* yvar  = (float*)d_out + 131072;         // [256,512,512]

    char* ws = (char*)d_ws;
    ushort* abt = (ushort*)ws;                          // 512 KB (A^T BK=64 images)
    float*  p2  = (float*)(ws + 512 * 1024);            // [256,4,512]   2 MB
    float*  yp  = (float*)(ws + 2560 * 1024);           // [8,256,512]   4 MB
    float*  tp  = (float*)(ws + 6656 * 1024);           // [8,256,512]   4 MB
    float*  xx  = (float*)(ws + 10752 * 1024);          // [256,512]     512 KB

    k_prep_at<<<128, 256, 0, stream>>>(A_mean, abt);
    k_fillz<<<2048, 256, 0, stream>>>(yvar);
    k_diag<<<512, 256, 0, stream>>>(x_var, x_mean, xx);
    k_t1<<<2048, 256, 0, stream>>>(x_mean, xx, A_mean, A_var, yp, tp);
    k_gemm2<<<4096, 512, 0, stream>>>(x_var, abt, A_mean, p2);
    k_final<<<512, 256, 0, stream>>>(yp, tp, p2, b_mean, b_var, ymean, yvar);
}

// Round 13
// 245.737 us; speedup vs baseline: 1.5818x; 1.1111x over previous
//
#include <hip/hip_runtime.h>
#include <hip/hip_bf16.h>

// B=256, IN=512, OUT=512
//   y_mean = x_mean @ A_mean + b_mean
//   y_var  = diag_embed( (diag(x_var)+x_mean^2) @ A_var + diag(A^T Cov A) + b_var )
// term2[b,o] = sum_i A[i,o] * (x_var[b] @ A)[i,o]  -> stacked GEMM + weighted colsum
//
// k_gemm2 (fat-tile, continuous pipeline): 256 blocks (1/CU), 8 waves, block
// 256x128, wave 64x64 (acc 64 VGPR -> 0.5 ds_reads/MFMA), BK=64, 64-iteration
// continuous loop over 8 mtiles. X: global->reg (2-deep banks) -> cvt -> XOR-
// swizzled LDS. A: glds from pre-swizzled images. Counted s_waitcnt vmcnt(8)
// keeps this iter's 8 X-loads in flight across the barrier; issue order pinned
// [p2st|fill|A] <sched_barrier> [X|compute|writeX]. y_var zero-fill fused
// in-loop. Epilogue per pass: barrier-free weighted colsum (A^T f32 weights),
// each wave's 64 rows = one p2[256][8][512] group.

typedef __bf16 bf16x8 __attribute__((ext_vector_type(8)));
typedef float f32x4 __attribute__((ext_vector_type(4)));

__device__ inline ushort f2bf(float f) {
    union { float f; unsigned u; } x; x.f = f;
    unsigned u = x.u + 0x7fffu + ((x.u >> 16) & 1u);   // RNE
    return (ushort)(u >> 16);
}

__device__ inline void gload16(const void* g, void* l) {
    __builtin_amdgcn_global_load_lds(
        (const __attribute__((address_space(1))) void*)g,
        (__attribute__((address_space(3))) void*)l, 16, 0, 0);
}

// ---- kernel 1: A_mean -> bf16 A^T tile images (BK=64): abt[(nt*8+ks)*16KB] ----
// image byte = r*128 + ((c ^ (r&7))*16) + e*2 ; value = A[ks*64+c*8+e][nt*128+r]
__global__ void k_prep_at(const float* __restrict__ am, ushort* __restrict__ abt) {
    int C = blockIdx.x * 256 + threadIdx.x;   // chunk id 0..32767
    int nt = C >> 13;
    int L  = C & 8191;
    int ks = L >> 10;
    int rem = L & 1023;
    int r = rem >> 3, cs = rem & 7;
    int c = cs ^ (r & 7);
    int o = nt * 128 + r;
    int j0 = ks * 64 + c * 8;
    ushort u[8];
    #pragma unroll
    for (int e = 0; e < 8; ++e) u[e] = f2bf(am[(j0 + e) * 512 + o]);
    *(int4*)(abt + (long)C * 8) = *(int4*)u;
}

// ---- kernel 1b: A^T f32 (for epilogue weights): atf[o][i] = A[i][o] ----
__global__ void k_prep_t(const float* __restrict__ am, float* __restrict__ atf) {
    __shared__ float tile[64][65];
    int t = threadIdx.x;
    int r0 = (blockIdx.x >> 3) * 64;   // i block
    int c0 = (blockIdx.x & 7) * 64;    // o block
    #pragma unroll
    for (int q = 0; q < 16; ++q) {
        int idx = q * 256 + t;
        int r = idx >> 6, c = idx & 63;
        tile[r][c] = am[(r0 + r) * 512 + c0 + c];
    }
    __syncthreads();
    #pragma unroll
    for (int q = 0; q < 16; ++q) {
        int idx = q * 256 + t;
        int ro = idx >> 6, co = idx & 63;
        atf[(c0 + ro) * 512 + r0 + co] = tile[co][ro];
    }
}

// ---- kernel 2: xx[b][i] = x_var[b,i,i] + x_mean^2 ----
__global__ void k_diag(const float* __restrict__ xv, const float* __restrict__ xm,
                       float* __restrict__ xx) {
    int idx = blockIdx.x * 256 + threadIdx.x;     // b*512+i
    int b = idx >> 9, i = idx & 511;
    float m = xm[idx];
    xx[idx] = xv[(long)b * 262144 + i * 513] + m * m;
}

// ---- kernel 3: partial small GEMMs: yp/tp[ic][b][o] over 64-i chunks ----
__global__ void k_t1(const float* __restrict__ xm, const float* __restrict__ xx,
                     const float* __restrict__ am, const float* __restrict__ av,
                     float* __restrict__ yp, float* __restrict__ tp) {
    __shared__ float S[2][64];
    int t = threadIdx.x;
    int b  = blockIdx.x >> 3;
    int ic = blockIdx.x & 7;
    int i0 = ic * 64;
    if (t < 128) {
        int which = t >> 6, ii = t & 63;
        const float* src = which ? xx : xm;
        S[which][ii] = src[b * 512 + i0 + ii];
    }
    __syncthreads();
    int mat = t >> 7;
    int o4 = t & 127;
    const float* M = mat ? av : am;
    const float* Sv = S[mat];
    f32x4 acc = {0.f, 0.f, 0.f, 0.f};
    #pragma unroll 8
    for (int ii = 0; ii < 64; ++ii) {
        f32x4 a = *(const f32x4*)(M + (long)(i0 + ii) * 512 + o4 * 4);
        float s = Sv[ii];
        acc[0] = fmaf(s, a[0], acc[0]);
        acc[1] = fmaf(s, a[1], acc[1]);
        acc[2] = fmaf(s, a[2], acc[2]);
        acc[3] = fmaf(s, a[3], acc[3]);
    }
    float* dst = (mat ? tp : yp) + ((long)ic * 256 + b) * 512 + o4 * 4;
    *(f32x4*)dst = acc;
}

// ---- kernel 4: fat-tile MFMA GEMM + fused zero-fill + colsum epilogue ----
__global__ __launch_bounds__(512, 2) void k_gemm2(
        const float*  __restrict__ xv,    // Xflat [131072][512] f32
        const ushort* __restrict__ abt,   // A^T BK=64 images [4][8][16KB]
        const float*  __restrict__ atf,   // A^T f32 [o][i]
        float* __restrict__ p2,           // [256][8][512]
        float* __restrict__ yvar)         // [256*512][512]
{
    __shared__ ushort ldsX[2][16384];     // 2 x 32KB bf16: 256 rows x 128B
    __shared__ ushort ldsA[2][8192];      // 2 x 16KB bf16: 128 rows x 128B

    int t = threadIdx.x;
    int lane = t & 63;
    int w = t >> 6;                       // 0..7
    int wm = w >> 1, wn = w & 1;          // 4 m-quarters x 2 n-halves
    int rl = lane & 15, g = lane >> 4;

    int bid = blockIdx.x;                 // 256 blocks
    int nt = (bid >> 3) & 3;
    int mgroup = (bid & 7) * 8 + (bid >> 5);   // partners (nt 0..3) same XCD

    f32x4 acc[4][4];
    #pragma unroll
    for (int mf = 0; mf < 4; ++mf)
        #pragma unroll
        for (int nf = 0; nf < 4; ++nf)
            acc[mf][nf] = (f32x4){0.f, 0.f, 0.f, 0.f};

    // X staging geometry: chunk q*512+t -> LDS byte q*8192 + t*16;
    // row = q*64 + (t>>3), phys chunk t&7 holds logical (t&7)^(row&7)
    int xrow = t >> 3;                    // 0..63
    int lc = (t & 7) ^ (xrow & 7);

    float4 xA[8], xB[8];

    auto xsrc = [&](int d) -> const float* {
        int mt = mgroup + ((d >> 3) << 6);     // mtile of data d
        return xv + ((long)mt * 256 + xrow) * 512 + (d & 7) * 64 + lc * 8;
    };
    auto loadX = [&](float4* xb, int d) {
        const float* s = xsrc(d);
        #pragma unroll
        for (int q = 0; q < 4; ++q) {
            xb[2 * q]     = *(const float4*)(s + (long)q * 32768);
            xb[2 * q + 1] = *(const float4*)(s + (long)q * 32768 + 4);
        }
    };
    auto writeX = [&](const float4* xb, int buf) {
        #pragma unroll
        for (int q = 0; q < 4; ++q) {
            bf16x8 v;
            v[0] = (__bf16)xb[2*q].x;   v[1] = (__bf16)xb[2*q].y;
            v[2] = (__bf16)xb[2*q].z;   v[3] = (__bf16)xb[2*q].w;
            v[4] = (__bf16)xb[2*q+1].x; v[5] = (__bf16)xb[2*q+1].y;
            v[6] = (__bf16)xb[2*q+1].z; v[7] = (__bf16)xb[2*q+1].w;
            *(bf16x8*)((char*)ldsX[buf] + q * 8192 + t * 16) = v;
        }
    };
    auto gldsA = [&](int buf, int ks) {
        const char* s = (const char*)abt + nt * 131072 + ks * 16384
                        + w * 2048 + lane * 16;
        char* d = (char*)ldsA[buf] + w * 2048;
        gload16(s, d);
        gload16(s + 1024, d + 1024);
    };
    auto compute = [&](int buf) {
        #pragma unroll
        for (int kc = 0; kc < 2; ++kc) {
            bf16x8 af[4], bfr[4];
            #pragma unroll
            for (int mf = 0; mf < 4; ++mf) {
                int r = wm * 64 + mf * 16 + rl;
                af[mf] = *(const bf16x8*)((const char*)ldsX[buf] + r * 128
                              + (((kc * 4 + g) ^ (r & 7)) << 4));
            }
            #pragma unroll
            for (int nf = 0; nf < 4; ++nf) {
                int ro = wn * 64 + nf * 16 + rl;
                bfr[nf] = *(const bf16x8*)((const char*)ldsA[buf] + ro * 128
                              + (((kc * 4 + g) ^ (ro & 7)) << 4));
            }
            #pragma unroll
            for (int mf = 0; mf < 4; ++mf)
                #pragma unroll
                for (int nf = 0; nf < 4; ++nf)
                    acc[mf][nf] = __builtin_amdgcn_mfma_f32_16x16x32_bf16(
                        af[mf], bfr[nf], acc[mf][nf], 0, 0, 0);
        }
    };
    auto fill = [&](int kk) {
        int mt = mgroup + ((kk >> 3) << 6);
        long rowb = (long)mt * 256 + (kk & 7) * 32;
        float4 z = make_float4(0.f, 0.f, 0.f, 0.f);
        #pragma unroll
        for (int q = 0; q < 2; ++q) {
            int ch = q * 512 + t;
            *(float4*)(yvar + (rowb + (ch >> 5)) * 512 + nt * 128 + (ch & 31) * 4) = z;
        }
    };
    auto epilogue = [&](int jj) {
        int mt = mgroup + jj * 64;
        int iB = ((mt & 1) << 8) + (wm << 6) + (g << 2);
        int oB = nt * 128 + (wn << 6) + rl;
        #pragma unroll
        for (int nf = 0; nf < 4; ++nf) {
            float p = 0.f;
            int o = oB + (nf << 4);
            #pragma unroll
            for (int mf = 0; mf < 4; ++mf) {
                f32x4 wv = *(const f32x4*)(atf + (long)o * 512 + iB + (mf << 4));
                p += wv[0] * acc[mf][nf][0] + wv[1] * acc[mf][nf][1]
                   + wv[2] * acc[mf][nf][2] + wv[3] * acc[mf][nf][3];
            }
            p += __shfl_xor(p, 16, 64);
            p += __shfl_xor(p, 32, 64);
            if (lane < 16)
                p2[((long)(mt >> 1) * 8 + ((mt & 1) * 4 + wm)) * 512 + o] = p;
        }
        #pragma unroll
        for (int mf = 0; mf < 4; ++mf)
            #pragma unroll
            for (int nf = 0; nf < 4; ++nf)
                acc[mf][nf] = (f32x4){0.f, 0.f, 0.f, 0.f};
    };

    // ---- prologue ----
    gldsA(0, 0);
    __builtin_amdgcn_sched_barrier(0);
    loadX(xA, 0);
    writeX(xA, 0);                         // compiler waits xA precisely
    loadX(xB, 1);
    asm volatile("s_waitcnt vmcnt(8) lgkmcnt(0)" ::: "memory");  // drain A0
    __builtin_amdgcn_s_barrier();
    __builtin_amdgcn_sched_barrier(0);

    // ---- 64 continuous iterations (2x unrolled for bank/buf parity) ----
    for (int kk2 = 0; kk2 < 32; ++kk2) {
        int kk = kk2 * 2;
        // even body (parity 0)
        if (kk && !(kk & 7)) epilogue((kk >> 3) - 1);
        fill(kk);
        gldsA(1, (kk + 1) & 7);
        __builtin_amdgcn_sched_barrier(0);     // pin [p2st|fill|A] before X
        if (kk < 62) loadX(xA, kk + 2);
        compute(0);
        writeX(xB, 1);                          // data kk+1
        if (kk < 62) asm volatile("s_waitcnt vmcnt(8) lgkmcnt(0)" ::: "memory");
        else         asm volatile("s_waitcnt vmcnt(0) lgkmcnt(0)" ::: "memory");
        __builtin_amdgcn_s_barrier();
        __builtin_amdgcn_sched_barrier(0);

        // odd body (parity 1), iter kk+1
        int k1 = kk + 1;
        fill(k1);
        if (k1 < 63) gldsA(0, (k1 + 1) & 7);
        __builtin_amdgcn_sched_barrier(0);
        if (k1 < 62) loadX(xB, k1 + 2);
        compute(1);
        if (k1 < 63) writeX(xA, 0);             // data k1+1
        if (k1 < 62) asm volatile("s_waitcnt vmcnt(8) lgkmcnt(0)" ::: "memory");
        else         asm volatile("s_waitcnt vmcnt(0) lgkmcnt(0)" ::: "memory");
        __builtin_amdgcn_s_barrier();
        __builtin_amdgcn_sched_barrier(0);
    }
    epilogue(7);
}

// ---- kernel 5: ymean = bm + sum(yp); yvar diag = bv + sum(tp) + sum(p2) ----
__global__ void k_final(const float* __restrict__ yp, const float* __restrict__ tp,
                        const float* __restrict__ p2,
                        const float* __restrict__ bm, const float* __restrict__ bv,
                        float* __restrict__ ymean, float* __restrict__ yvar) {
    int idx = blockIdx.x * 256 + threadIdx.x;    // b*512+o
    int b = idx >> 9, o = idx & 511;
    float ym = bm[o], t1 = bv[o];
    #pragma unroll
    for (int ic = 0; ic < 8; ++ic) {
        ym += yp[((long)ic * 256 + b) * 512 + o];
        t1 += tp[((long)ic * 256 + b) * 512 + o];
    }
    #pragma unroll
    for (int s = 0; s < 8; ++s)
        t1 += p2[((long)b * 8 + s) * 512 + o];
    ymean[idx] = ym;
    yvar[(long)idx * 512 + o] = t1;
}

extern "C" void kernel_launch(void* const* d_in, const int* in_sizes, int n_in,
                              void* d_out, int out_size, void* d_ws, size_t ws_size,
                              hipStream_t stream) {
    const float* x_mean = (const float*)d_in[0];
    const float* x_var  = (const float*)d_in[1];
    const float* A_mean = (const float*)d_in[2];
    const float* A_var  = (const float*)d_in[3];
    const float* b_mean = (const float*)d_in[4];
    const float* b_var  = (const float*)d_in[5];

    float* ymean = (float*)d_out;                  // [256,512]
    float* yvar  = (float*)d_out + 131072;         // [256,512,512]

    char* ws = (char*)d_ws;
    ushort* abt = (ushort*)ws;                          // 512 KB (A^T images)
    float*  atf = (float*)(ws + 512 * 1024);            // A^T f32      1 MB
    float*  p2  = (float*)(ws + 1536 * 1024);           // [256,8,512]  4 MB
    float*  yp  = (float*)(ws + 5632 * 1024);           // [8,256,512]  4 MB
    float*  tp  = (float*)(ws + 9728 * 1024);           // [8,256,512]  4 MB
    float*  xx  = (float*)(ws + 13824 * 1024);          // [256,512]    512 KB

    k_prep_at<<<128, 256, 0, stream>>>(A_mean, abt);
    k_prep_t<<<64, 256, 0, stream>>>(A_mean, atf);
    k_diag<<<512, 256, 0, stream>>>(x_var, x_mean, xx);
    k_t1<<<2048, 256, 0, stream>>>(x_mean, xx, A_mean, A_var, yp, tp);
    k_gemm2<<<256, 512, 0, stream>>>(x_var, abt, atf, p2, yvar);
    k_final<<<512, 256, 0, stream>>>(yp, tp, p2, b_mean, b_var, ymean, yvar);
}